// Round 5
// baseline (109.768 us; speedup 1.0000x reference)
//
#include <hip/hip_runtime.h>
#include <hip/hip_bf16.h>

// CapsuleNet dynamic routing, fused per-sample. fp32 I/O:
// x: f32 [8192, 32, 8], W: f32 [32, 8, 256], out: f32 [8192, 16, 16].
// One block = S samples; thread t = (nc = t>>4, dc = t&15) owns column k = t.
// r15: x as wave-uniform s_loads. r16: b128 c-reads, transposed b_lds.
// r17/r18: (256,6) + CSTRIDE 44 (spill fix). r19: S=4, (256,4) — W-refetch
// theory: only −1.2 us => falsified (W was L2-absorbed/overlapped).
// r20 (this round): x s_loads -> per-lane VMEM uniform-address b128 loads.
// Theory: u_hat needs 2KB x/block = 512 dwords through ~48 SGPRs -> the
// compiler re-issues s_loads all through the ic-loop with shallow pipeline,
// serializing dot2 groups on lgkmcnt (~200cyc SMEM latency, ~2-3k cyc/wave
// exposed — the gap between u_hat's ~3us dot2 floor and its ~17us share).
// VMEM path: deep vmcnt queue + VGPR destinations -> pipelined. Address
// uniformity is hidden from the compiler via a memory-sourced divergent
// zero (zbuf in workspace slack; prep writes it), so it can't scalarize.

#define S 4

typedef float    v2f __attribute__((ext_vector_type(2)));
typedef float    v4f __attribute__((ext_vector_type(4)));
typedef _Float16 v2h __attribute__((ext_vector_type(2)));
typedef _Float16 v8h __attribute__((ext_vector_type(8)));

__device__ __forceinline__ v2h pack2h(float a, float b) {
  return __builtin_bit_cast(v2h, __builtin_amdgcn_cvt_pkrtz(a, b));  // v_cvt_pkrtz_f16_f32
}

// DPP cross-lane: value of `x` from lane (lane ^ k) within a 16-lane row.
// 0xB1 = quad_perm[1,0,3,2] (xor1)  0x4E = quad_perm[2,3,0,1] (xor2)
// 0x128 = row_ror:8 (xor8)  0x141 = row_half_mirror  0x140 = row_mirror
template <int CTRL>
__device__ __forceinline__ float dppf(float x) {
  return __builtin_bit_cast(float,
      __builtin_amdgcn_update_dpp(0, __builtin_bit_cast(int, x), CTRL, 0xF, 0xF, true));
}
template <int CTRL>
__device__ __forceinline__ v2h dpph(v2h v) {  // both samples in one DPP
  return __builtin_bit_cast(v2h,
      __builtin_amdgcn_update_dpp(0, __builtin_bit_cast(int, v), CTRL, 0xF, 0xF, true));
}
// Masked DPP keeping `old` on disabled banks (bound_ctrl=false: keep old).
template <int CTRL, int BANK>
__device__ __forceinline__ int dpp_old_i(int old, int x) {
  return __builtin_amdgcn_update_dpp(old, x, CTRL, 0xF, BANK, false);
}
// Deliver partner(lane^4)'s value of s to every lane (validated r10/r13):
// banks 0,2 (lanes 0-3,8-11): from lane+4 via row_shl:4 (0x104);
// banks 1,3 (lanes 4-7,12-15): from lane-4 via row_shr:4 (0x114).
__device__ __forceinline__ v2h xor4t_h(v2h s) {
  int si = __builtin_bit_cast(int, s);
  int ya = dpp_old_i<0x104, 0x5>(0, si);
  return __builtin_bit_cast(v2h, dpp_old_i<0x114, 0xA>(ya, si));
}

#if __has_builtin(__builtin_amdgcn_fdot2)
__device__ __forceinline__ float dot2(v2h a, v2h b, float c) {
  return __builtin_amdgcn_fdot2(a, b, c, false);  // v_dot2_f32_f16
}
#else
__device__ __forceinline__ float dot2(v2h a, v2h b, float c) {
  return fmaf((float)a.x, (float)b.x, fmaf((float)a.y, (float)b.y, c));
}
#endif

#define ZBUF_HALF_OFF 2097152  // zbuf sits at xh + 4MB (workspace slack)

// Fused prep: blocks 0..255: W[ic][id][k](f32) -> Wth[ic][k][id](f16), NO
// permute; blocks 256..1279: x (f32) -> xh (f16), 8 elems/thread;
// block 1280: divergent-zero buffer (64 words) for caps' x-load indexing.
__global__ __launch_bounds__(256) void prep_kernel(const float* __restrict__ W,
                                                   const float* __restrict__ x,
                                                   _Float16* __restrict__ Wth,
                                                   _Float16* __restrict__ xh) {
  int bid = blockIdx.x;
  if (bid >= 1280) {
    if (threadIdx.x < 64)
      ((unsigned*)(xh + ZBUF_HALF_OFF))[threadIdx.x] = 0u;
    return;
  }
  if (bid < 256) {
    int o  = bid * 256 + threadIdx.x;
    int ic = o >> 11;
    int k  = (o >> 3) & 255;
    int id = o & 7;
    Wth[o] = (_Float16)W[(ic * 8 + id) * 256 + k];
  } else {
    int tid = (bid - 256) * 256 + threadIdx.x;
    const float4* xp = (const float4*)x + tid * 2;
    float4 f0 = xp[0], f1 = xp[1];
    v2h h0 = {(_Float16)f0.x, (_Float16)f0.y};
    v2h h1 = {(_Float16)f0.z, (_Float16)f0.w};
    v2h h2 = {(_Float16)f1.x, (_Float16)f1.y};
    v2h h3 = {(_Float16)f1.z, (_Float16)f1.w};
    uint4 o;
    o.x = __builtin_bit_cast(unsigned, h0);
    o.y = __builtin_bit_cast(unsigned, h1);
    o.z = __builtin_bit_cast(unsigned, h2);
    o.w = __builtin_bit_cast(unsigned, h3);
    ((uint4*)xh)[tid] = o;
  }
}

// squash over the 16 dc lanes, both samples at once; DPP-only reduction (f32).
__device__ __forceinline__ v2f squash2(v2f o) {
  v2f s2 = o * o;
  s2.x += dppf<0xB1>(s2.x);   s2.y += dppf<0xB1>(s2.y);    // + lane^1
  s2.x += dppf<0x4E>(s2.x);   s2.y += dppf<0x4E>(s2.y);    // + lane^2
  s2.x += dppf<0x141>(s2.x);  s2.y += dppf<0x141>(s2.y);   // + lane^7
  s2.x += dppf<0x140>(s2.x);  s2.y += dppf<0x140>(s2.y);   // + lane^15
  s2 += (v2f){1e-7f, 1e-7f};
  v2f sc;
  sc.x = s2.x * __builtin_amdgcn_rsqf(s2.x) * __builtin_amdgcn_rcpf(1.f + s2.x);
  sc.y = s2.y * __builtin_amdgcn_rsqf(s2.y) * __builtin_amdgcn_rcpf(1.f + s2.y);
  return o * sc;  // sqrt(s2)/(1+s2) * o
}

// Butterfly transpose-reduction on NORMAL-order packed-f16 uh (selects are
// single 32-bit cndmasks moving both samples). Lane dc lands b[icb+dc][nc]
// (f32, transposed layout: bp* pre-offset to &b_lds[s][dc][nc], row stride
// 20 floats; icb*20 is a compile-time ds offset immediate).
// Levels 8/2/1 via DPP xor; level 4 via the masked dual-DPP transport.
template <bool ASSIGN>
__device__ __forceinline__ void b_update2(v2h vh, const v2h* uh, int dc,
                                          float* bp0, float* bp1) {
#pragma unroll
  for (int icb = 0; icb < 32; icb += 16) {
    v2h a[16];
#pragma unroll
    for (int j = 0; j < 16; ++j) a[j] = vh * uh[icb + j];  // pk_mul_f16
    v2h b8[8];
    const bool u8 = (dc & 8) != 0;
#pragma unroll
    for (int j = 0; j < 8; ++j) {
      v2h send = u8 ? a[j] : a[j + 8];
      v2h recv = dpph<0x128>(send);              // partner(lane^8)'s send
      b8[j] = (u8 ? a[j + 8] : a[j]) + recv;
    }
    v2h c4[4];
    const bool u4 = (dc & 4) != 0;
#pragma unroll
    for (int j = 0; j < 4; ++j) {
      v2h send = u4 ? b8[j] : b8[j + 4];
      v2h recv = xor4t_h(send);                  // partner(lane^4)'s send
      c4[j] = (u4 ? b8[j + 4] : b8[j]) + recv;
    }
    v2h d2[2];
    const bool u2 = (dc & 2) != 0;
#pragma unroll
    for (int j = 0; j < 2; ++j) {
      v2h send = u2 ? c4[j] : c4[j + 2];
      v2h recv = dpph<0x4E>(send);               // partner(lane^2)'s send
      d2[j] = (u2 ? c4[j + 2] : c4[j]) + recv;
    }
    const bool u1 = (dc & 1) != 0;
    v2h send = u1 ? d2[0] : d2[1];
    v2h recv = dpph<0xB1>(send);                 // partner(lane^1)'s send
    v2h e = (u1 ? d2[1] : d2[0]) + recv;
    float e0 = (float)e.x, e1 = (float)e.y;
    if (ASSIGN) { bp0[icb * 20] = e0;  bp1[icb * 20] = e1; }
    else        { bp0[icb * 20] += e0; bp1[icb * 20] += e1; }
  }
}

#define CSTRIDE 44  // v2h per c-row: 176 B rows (16B-aligned). Read side: 4
                    // nc-row b128 broadcasts start at banks (12nc+4blk)%32 ->
                    // 4 disjoint 4-bank spans. Write side: 2 lanes/bank (free).

__global__ __launch_bounds__(256, 4) void caps_kernel(const _Float16* __restrict__ xh,
                                                      const uint4* __restrict__ Wt4,
                                                      float* __restrict__ out) {
  const int t  = threadIdx.x;
  const int nc = t >> 4;
  const int dc = t & 15;
  const int s0 = blockIdx.x * S;

  // b transposed: [sample][ic 0..31][nc 0..15 padded to 20].
  // softmax reads b[ss][ic][8q..8q+7] as TWO ds_read_b128 (16B-aligned).
  __shared__ __align__(16) float b_lds[S][32][20];
  __shared__ __align__(16) v2h cAh[16 * CSTRIDE];  // c pairs, samples (0,1)
  __shared__ __align__(16) v2h cBh[16 * CSTRIDE];  // c pairs, samples (2,3)

  v2h uhA[32], uhB[32];                // packed (s0,s1) / (s2,s3)
  v2f oA = (v2f){0.f, 0.f};
  v2f oB = (v2f){0.f, 0.f};

  // Divergent zero: defeats uniformity analysis on the x addresses below so
  // they stay VMEM (per-lane global_load_dwordx4, broadcast by coalescer,
  // deep vmcnt pipelining) instead of SGPR-starved s_load chains.
  const unsigned z = ((const unsigned*)(xh + ZBUF_HALF_OFF))[t & 63];

  // ---- u_hat: uniform-address VMEM x + ONE b128 W load per ic, amortized
  //      over 4 samples ----
  const uint4* xq0 = (const uint4*)(xh + (s0 + 0) * 256);  // 32 x 16B rows
  const uint4* xq1 = (const uint4*)(xh + (s0 + 1) * 256);
  const uint4* xq2 = (const uint4*)(xh + (s0 + 2) * 256);
  const uint4* xq3 = (const uint4*)(xh + (s0 + 3) * 256);
#pragma unroll
  for (int ic = 0; ic < 32; ++ic) {
    uint4 wv = Wt4[ic * 256 + t];  // 8 f16 weights, one coalesced dwordx4
    v2h w0 = __builtin_bit_cast(v2h, wv.x);
    v2h w1 = __builtin_bit_cast(v2h, wv.y);
    v2h w2 = __builtin_bit_cast(v2h, wv.z);
    v2h w3 = __builtin_bit_cast(v2h, wv.w);
    uint4 x0 = xq0[ic + z];  // 16B of x[s][ic][:], same addr all lanes
    uint4 x1 = xq1[ic + z];
    uint4 x2 = xq2[ic + z];
    uint4 x3 = xq3[ic + z];
    float a0 = dot2(__builtin_bit_cast(v2h, x0.w), w3,
               dot2(__builtin_bit_cast(v2h, x0.z), w2,
               dot2(__builtin_bit_cast(v2h, x0.y), w1,
               dot2(__builtin_bit_cast(v2h, x0.x), w0, 0.f))));
    float a1 = dot2(__builtin_bit_cast(v2h, x1.w), w3,
               dot2(__builtin_bit_cast(v2h, x1.z), w2,
               dot2(__builtin_bit_cast(v2h, x1.y), w1,
               dot2(__builtin_bit_cast(v2h, x1.x), w0, 0.f))));
    float a2 = dot2(__builtin_bit_cast(v2h, x2.w), w3,
               dot2(__builtin_bit_cast(v2h, x2.z), w2,
               dot2(__builtin_bit_cast(v2h, x2.y), w1,
               dot2(__builtin_bit_cast(v2h, x2.x), w0, 0.f))));
    float a3 = dot2(__builtin_bit_cast(v2h, x3.w), w3,
               dot2(__builtin_bit_cast(v2h, x3.z), w2,
               dot2(__builtin_bit_cast(v2h, x3.y), w1,
               dot2(__builtin_bit_cast(v2h, x3.x), w0, 0.f))));
    oA += (v2f){a0, a1};
    oB += (v2f){a2, a3};
    uhA[ic] = pack2h(a0, a1);
    uhB[ic] = pack2h(a2, a3);
  }

  float* bp0 = &b_lds[0][dc][nc];  // transposed-target bases for this thread
  float* bp1 = &b_lds[1][dc][nc];
  float* bp2 = &b_lds[2][dc][nc];
  float* bp3 = &b_lds[3][dc][nc];

  // ---- routing round 0: b = 0 => c = 1/16 ----
  {
    v2f vA = squash2(oA * (v2f){0.0625f, 0.0625f});
    v2f vB = squash2(oB * (v2f){0.0625f, 0.0625f});
    b_update2<true>(pack2h(vA.x, vA.y), uhA, dc, bp0, bp1);
    b_update2<true>(pack2h(vB.x, vB.y), uhB, dc, bp2, bp3);
  }
  __syncthreads();

  // ---- rounds 1, 2 ----
#pragma unroll
  for (int r = 1; r < 3; ++r) {
    {  // distributed softmax over nc: 256 threads. thread -> (ss, ic, half)
      const int ss  = t >> 6;         // sample 0..3 (wave-uniform)
      const int icc = (t >> 1) & 31;  // column (ic)
      const int q   = t & 1;          // nc rows 8q..8q+7
      // no max-subtraction: |b| bounded far below exp overflow; shift-invariant.
      const v4f bL = *(const v4f*)&b_lds[ss][icc][8 * q + 0];  // ds_read_b128
      const v4f bH = *(const v4f*)&b_lds[ss][icc][8 * q + 4];  // ds_read_b128
      float e0 = __expf(bL.x), e1 = __expf(bL.y), e2 = __expf(bL.z), e3 = __expf(bL.w);
      float e4 = __expf(bH.x), e5 = __expf(bH.y), e6 = __expf(bH.z), e7 = __expf(bH.w);
      float ps = ((e0 + e1) + (e2 + e3)) + ((e4 + e5) + (e6 + e7));
      ps += dppf<0xB1>(ps);  // + lane^1 (partner half) -> full 16-row sum
      float inv = __builtin_amdgcn_rcpf(ps);
      _Float16* cw = (_Float16*)(ss < 2 ? cAh : cBh) + (ss & 1);  // pair component
      cw[((8 * q + 0) * CSTRIDE + icc) * 2] = (_Float16)(e0 * inv);
      cw[((8 * q + 1) * CSTRIDE + icc) * 2] = (_Float16)(e1 * inv);
      cw[((8 * q + 2) * CSTRIDE + icc) * 2] = (_Float16)(e2 * inv);
      cw[((8 * q + 3) * CSTRIDE + icc) * 2] = (_Float16)(e3 * inv);
      cw[((8 * q + 4) * CSTRIDE + icc) * 2] = (_Float16)(e4 * inv);
      cw[((8 * q + 5) * CSTRIDE + icc) * 2] = (_Float16)(e5 * inv);
      cw[((8 * q + 6) * CSTRIDE + icc) * 2] = (_Float16)(e6 * inv);
      cw[((8 * q + 7) * CSTRIDE + icc) * 2] = (_Float16)(e7 * inv);
    }
    __syncthreads();

    // c.uh: 8 ds_read_b128 broadcasts per table (4 ic-pairs per b128).
    const v8h* crA = (const v8h*)(cAh + nc * CSTRIDE);
    const v8h* crB = (const v8h*)(cBh + nc * CSTRIDE);
    v2h ohA = (v2h){(_Float16)0.f, (_Float16)0.f};
    v2h ohB = (v2h){(_Float16)0.f, (_Float16)0.f};
#pragma unroll
    for (int blk = 0; blk < 4; ++blk) {
      uint4 ua = __builtin_bit_cast(uint4, crA[blk]);      // ic 4blk..4blk+3
      uint4 ub = __builtin_bit_cast(uint4, crA[blk + 4]);  // ic 16+4blk..
      ohA = __builtin_elementwise_fma(__builtin_bit_cast(v2h, ua.x), uhA[4 * blk + 0], ohA);
      ohA = __builtin_elementwise_fma(__builtin_bit_cast(v2h, ua.y), uhA[4 * blk + 1], ohA);
      ohA = __builtin_elementwise_fma(__builtin_bit_cast(v2h, ua.z), uhA[4 * blk + 2], ohA);
      ohA = __builtin_elementwise_fma(__builtin_bit_cast(v2h, ua.w), uhA[4 * blk + 3], ohA);
      ohA = __builtin_elementwise_fma(__builtin_bit_cast(v2h, ub.x), uhA[16 + 4 * blk + 0], ohA);
      ohA = __builtin_elementwise_fma(__builtin_bit_cast(v2h, ub.y), uhA[16 + 4 * blk + 1], ohA);
      ohA = __builtin_elementwise_fma(__builtin_bit_cast(v2h, ub.z), uhA[16 + 4 * blk + 2], ohA);
      ohA = __builtin_elementwise_fma(__builtin_bit_cast(v2h, ub.w), uhA[16 + 4 * blk + 3], ohA);
      uint4 va = __builtin_bit_cast(uint4, crB[blk]);
      uint4 vb = __builtin_bit_cast(uint4, crB[blk + 4]);
      ohB = __builtin_elementwise_fma(__builtin_bit_cast(v2h, va.x), uhB[4 * blk + 0], ohB);
      ohB = __builtin_elementwise_fma(__builtin_bit_cast(v2h, va.y), uhB[4 * blk + 1], ohB);
      ohB = __builtin_elementwise_fma(__builtin_bit_cast(v2h, va.z), uhB[4 * blk + 2], ohB);
      ohB = __builtin_elementwise_fma(__builtin_bit_cast(v2h, va.w), uhB[4 * blk + 3], ohB);
      ohB = __builtin_elementwise_fma(__builtin_bit_cast(v2h, vb.x), uhB[16 + 4 * blk + 0], ohB);
      ohB = __builtin_elementwise_fma(__builtin_bit_cast(v2h, vb.y), uhB[16 + 4 * blk + 1], ohB);
      ohB = __builtin_elementwise_fma(__builtin_bit_cast(v2h, vb.z), uhB[16 + 4 * blk + 2], ohB);
      ohB = __builtin_elementwise_fma(__builtin_bit_cast(v2h, vb.w), uhB[16 + 4 * blk + 3], ohB);
    }
    v2f vA = squash2((v2f){(float)ohA.x, (float)ohA.y});
    v2f vB = squash2((v2f){(float)ohB.x, (float)ohB.y});
    if (r == 2) {
      out[(s0 + 0) * 256 + t] = vA.x;
      out[(s0 + 1) * 256 + t] = vA.y;
      out[(s0 + 2) * 256 + t] = vB.x;
      out[(s0 + 3) * 256 + t] = vB.y;
    } else {
      b_update2<false>(pack2h(vA.x, vA.y), uhA, dc, bp0, bp1);
      b_update2<false>(pack2h(vB.x, vB.y), uhB, dc, bp2, bp3);
      __syncthreads();  // b complete before round-2 softmax; c overwrite safe
    }
  }
}

extern "C" void kernel_launch(void* const* d_in, const int* in_sizes, int n_in,
                              void* d_out, int out_size, void* d_ws, size_t ws_size,
                              hipStream_t stream) {
  const float* x = (const float*)d_in[0];
  const float* W = (const float*)d_in[1];
  _Float16* Wth = (_Float16*)d_ws;           // 128 KB: f16 W-transpose
  _Float16* xh  = (_Float16*)d_ws + 65536;   // 4 MB: f16 x (+256B zbuf after)

  prep_kernel<<<1281, 256, 0, stream>>>(W, x, Wth, xh);
  caps_kernel<<<8192 / S, 256, 0, stream>>>(xh, (const uint4*)Wth, (float*)d_out);
}

// Round 6
// 97.692 us; speedup vs baseline: 1.1236x; 1.1236x over previous
//
#include <hip/hip_runtime.h>
#include <hip/hip_bf16.h>

// CapsuleNet dynamic routing, fused per-sample. fp32 I/O:
// x: f32 [8192, 32, 8], W: f32 [32, 8, 256], out: f32 [8192, 16, 16].
// One block = S samples; thread t = (nc = t>>4, dc = t&15) owns column k = t.
// r15: x as wave-uniform s_loads. r16: b128 c-reads, transposed b_lds.
// r17/r18: (256,6) + CSTRIDE 44 (spill fix). r19: S=4, (256,4): -1.2us.
// r20: per-lane uniform-addr VMEM x: caps 43->57us REGRESSION (160 extra
// VMEM issues + addr math + z-dependency; scalar-pipe parallelism lost).
// r21 (this round): x broadcast via VGPR-resident block + compile-time
// v_readlane. Each wave loads the FULL 2KB x-block into 8 VGPRs/lane
// (2 coalesced dwordx4: lane l holds dwords 8l..8l+7). dword(s,ic,d) lives
// at lane 16s+(ic>>1), slot (ic&1)*4+d — both compile-time under full
// unroll -> readlane to SGPR feeds dot2 src0 directly. No SMEM capacity
// serialization (the r19 stall: 512 x-dwords through ~48 SGPRs), no VMEM
// per-load overhead (the r20 mistake). +512 readlanes (~3.4us VALU) buys
// removal of all x-transport stalls.

#define S 4

typedef float    v2f __attribute__((ext_vector_type(2)));
typedef float    v4f __attribute__((ext_vector_type(4)));
typedef _Float16 v2h __attribute__((ext_vector_type(2)));
typedef _Float16 v8h __attribute__((ext_vector_type(8)));

__device__ __forceinline__ v2h pack2h(float a, float b) {
  return __builtin_bit_cast(v2h, __builtin_amdgcn_cvt_pkrtz(a, b));  // v_cvt_pkrtz_f16_f32
}

// DPP cross-lane: value of `x` from lane (lane ^ k) within a 16-lane row.
// 0xB1 = quad_perm[1,0,3,2] (xor1)  0x4E = quad_perm[2,3,0,1] (xor2)
// 0x128 = row_ror:8 (xor8)  0x141 = row_half_mirror  0x140 = row_mirror
template <int CTRL>
__device__ __forceinline__ float dppf(float x) {
  return __builtin_bit_cast(float,
      __builtin_amdgcn_update_dpp(0, __builtin_bit_cast(int, x), CTRL, 0xF, 0xF, true));
}
template <int CTRL>
__device__ __forceinline__ v2h dpph(v2h v) {  // both samples in one DPP
  return __builtin_bit_cast(v2h,
      __builtin_amdgcn_update_dpp(0, __builtin_bit_cast(int, v), CTRL, 0xF, 0xF, true));
}
// Masked DPP keeping `old` on disabled banks (bound_ctrl=false: keep old).
template <int CTRL, int BANK>
__device__ __forceinline__ int dpp_old_i(int old, int x) {
  return __builtin_amdgcn_update_dpp(old, x, CTRL, 0xF, BANK, false);
}
// Deliver partner(lane^4)'s value of s to every lane (validated r10/r13):
// banks 0,2 (lanes 0-3,8-11): from lane+4 via row_shl:4 (0x104);
// banks 1,3 (lanes 4-7,12-15): from lane-4 via row_shr:4 (0x114).
__device__ __forceinline__ v2h xor4t_h(v2h s) {
  int si = __builtin_bit_cast(int, s);
  int ya = dpp_old_i<0x104, 0x5>(0, si);
  return __builtin_bit_cast(v2h, dpp_old_i<0x114, 0xA>(ya, si));
}

#if __has_builtin(__builtin_amdgcn_fdot2)
__device__ __forceinline__ float dot2(v2h a, v2h b, float c) {
  return __builtin_amdgcn_fdot2(a, b, c, false);  // v_dot2_f32_f16
}
#else
__device__ __forceinline__ float dot2(v2h a, v2h b, float c) {
  return fmaf((float)a.x, (float)b.x, fmaf((float)a.y, (float)b.y, c));
}
#endif

// x dword broadcast: value of slot SLOT (of the 8 per-lane x dwords) held
// by lane `lane` of this wave, as an f16 pair in an SGPR. SLOT and lane are
// compile-time under full unroll -> v_readlane_b32 s, v, imm.
template <int SLOT>
__device__ __forceinline__ v2h xlane(const uint4& x0, const uint4& x1, int lane) {
  unsigned v;
  if constexpr (SLOT == 0) v = x0.x; else if constexpr (SLOT == 1) v = x0.y;
  else if constexpr (SLOT == 2) v = x0.z; else if constexpr (SLOT == 3) v = x0.w;
  else if constexpr (SLOT == 4) v = x1.x; else if constexpr (SLOT == 5) v = x1.y;
  else if constexpr (SLOT == 6) v = x1.z; else v = x1.w;
  return __builtin_bit_cast(v2h, __builtin_amdgcn_readlane(v, lane));
}

// Fused prep: blocks 0..255: W[ic][id][k](f32) -> Wth[ic][k][id](f16), NO
// permute; blocks 256..1279: x (f32) -> xh (f16), 8 elems/thread.
__global__ __launch_bounds__(256) void prep_kernel(const float* __restrict__ W,
                                                   const float* __restrict__ x,
                                                   _Float16* __restrict__ Wth,
                                                   _Float16* __restrict__ xh) {
  int bid = blockIdx.x;
  if (bid < 256) {
    int o  = bid * 256 + threadIdx.x;
    int ic = o >> 11;
    int k  = (o >> 3) & 255;
    int id = o & 7;
    Wth[o] = (_Float16)W[(ic * 8 + id) * 256 + k];
  } else {
    int tid = (bid - 256) * 256 + threadIdx.x;
    const float4* xp = (const float4*)x + tid * 2;
    float4 f0 = xp[0], f1 = xp[1];
    v2h h0 = {(_Float16)f0.x, (_Float16)f0.y};
    v2h h1 = {(_Float16)f0.z, (_Float16)f0.w};
    v2h h2 = {(_Float16)f1.x, (_Float16)f1.y};
    v2h h3 = {(_Float16)f1.z, (_Float16)f1.w};
    uint4 o;
    o.x = __builtin_bit_cast(unsigned, h0);
    o.y = __builtin_bit_cast(unsigned, h1);
    o.z = __builtin_bit_cast(unsigned, h2);
    o.w = __builtin_bit_cast(unsigned, h3);
    ((uint4*)xh)[tid] = o;
  }
}

// squash over the 16 dc lanes, both samples at once; DPP-only reduction (f32).
__device__ __forceinline__ v2f squash2(v2f o) {
  v2f s2 = o * o;
  s2.x += dppf<0xB1>(s2.x);   s2.y += dppf<0xB1>(s2.y);    // + lane^1
  s2.x += dppf<0x4E>(s2.x);   s2.y += dppf<0x4E>(s2.y);    // + lane^2
  s2.x += dppf<0x141>(s2.x);  s2.y += dppf<0x141>(s2.y);   // + lane^7
  s2.x += dppf<0x140>(s2.x);  s2.y += dppf<0x140>(s2.y);   // + lane^15
  s2 += (v2f){1e-7f, 1e-7f};
  v2f sc;
  sc.x = s2.x * __builtin_amdgcn_rsqf(s2.x) * __builtin_amdgcn_rcpf(1.f + s2.x);
  sc.y = s2.y * __builtin_amdgcn_rsqf(s2.y) * __builtin_amdgcn_rcpf(1.f + s2.y);
  return o * sc;  // sqrt(s2)/(1+s2) * o
}

// Butterfly transpose-reduction on NORMAL-order packed-f16 uh (selects are
// single 32-bit cndmasks moving both samples). Lane dc lands b[icb+dc][nc]
// (f32, transposed layout: bp* pre-offset to &b_lds[s][dc][nc], row stride
// 20 floats; icb*20 is a compile-time ds offset immediate).
// Levels 8/2/1 via DPP xor; level 4 via the masked dual-DPP transport.
template <bool ASSIGN>
__device__ __forceinline__ void b_update2(v2h vh, const v2h* uh, int dc,
                                          float* bp0, float* bp1) {
#pragma unroll
  for (int icb = 0; icb < 32; icb += 16) {
    v2h a[16];
#pragma unroll
    for (int j = 0; j < 16; ++j) a[j] = vh * uh[icb + j];  // pk_mul_f16
    v2h b8[8];
    const bool u8 = (dc & 8) != 0;
#pragma unroll
    for (int j = 0; j < 8; ++j) {
      v2h send = u8 ? a[j] : a[j + 8];
      v2h recv = dpph<0x128>(send);              // partner(lane^8)'s send
      b8[j] = (u8 ? a[j + 8] : a[j]) + recv;
    }
    v2h c4[4];
    const bool u4 = (dc & 4) != 0;
#pragma unroll
    for (int j = 0; j < 4; ++j) {
      v2h send = u4 ? b8[j] : b8[j + 4];
      v2h recv = xor4t_h(send);                  // partner(lane^4)'s send
      c4[j] = (u4 ? b8[j + 4] : b8[j]) + recv;
    }
    v2h d2[2];
    const bool u2 = (dc & 2) != 0;
#pragma unroll
    for (int j = 0; j < 2; ++j) {
      v2h send = u2 ? c4[j] : c4[j + 2];
      v2h recv = dpph<0x4E>(send);               // partner(lane^2)'s send
      d2[j] = (u2 ? c4[j + 2] : c4[j]) + recv;
    }
    const bool u1 = (dc & 1) != 0;
    v2h send = u1 ? d2[0] : d2[1];
    v2h recv = dpph<0xB1>(send);                 // partner(lane^1)'s send
    v2h e = (u1 ? d2[1] : d2[0]) + recv;
    float e0 = (float)e.x, e1 = (float)e.y;
    if (ASSIGN) { bp0[icb * 20] = e0;  bp1[icb * 20] = e1; }
    else        { bp0[icb * 20] += e0; bp1[icb * 20] += e1; }
  }
}

#define CSTRIDE 44  // v2h per c-row: 176 B rows (16B-aligned). Read side: 4
                    // nc-row b128 broadcasts start at banks (12nc+4blk)%32 ->
                    // 4 disjoint 4-bank spans. Write side: 2 lanes/bank (free).

__global__ __launch_bounds__(256, 4) void caps_kernel(const _Float16* __restrict__ xh,
                                                      const uint4* __restrict__ Wt4,
                                                      float* __restrict__ out) {
  const int t  = threadIdx.x;
  const int nc = t >> 4;
  const int dc = t & 15;
  const int s0 = blockIdx.x * S;

  // b transposed: [sample][ic 0..31][nc 0..15 padded to 20].
  // softmax reads b[ss][ic][8q..8q+7] as TWO ds_read_b128 (16B-aligned).
  __shared__ __align__(16) float b_lds[S][32][20];
  __shared__ __align__(16) v2h cAh[16 * CSTRIDE];  // c pairs, samples (0,1)
  __shared__ __align__(16) v2h cBh[16 * CSTRIDE];  // c pairs, samples (2,3)

  v2h uhA[32], uhB[32];                // packed (s0,s1) / (s2,s3)
  v2f oA = (v2f){0.f, 0.f};
  v2f oB = (v2f){0.f, 0.f};

  // ---- x block (4 samples x 512B = 2KB) into 8 VGPRs per lane: every wave
  // holds the whole block; lane l owns dwords 8l..8l+7 (2 coalesced b128).
  const uint4* xw = (const uint4*)(xh + s0 * 256);  // 128 uint4 = 2KB
  const int lane = t & 63;
  const uint4 xr0 = xw[lane * 2 + 0];
  const uint4 xr1 = xw[lane * 2 + 1];

  // ---- u_hat: readlane x broadcast + ONE b128 W load per ic, amortized
  //      over 4 samples. dword(s,ic,d): lane 16s+(ic>>1), slot (ic&1)*4+d.
#pragma unroll
  for (int ic = 0; ic < 32; ++ic) {
    uint4 wv = Wt4[ic * 256 + t];  // 8 f16 weights, one coalesced dwordx4
    v2h w0 = __builtin_bit_cast(v2h, wv.x);
    v2h w1 = __builtin_bit_cast(v2h, wv.y);
    v2h w2 = __builtin_bit_cast(v2h, wv.z);
    v2h w3 = __builtin_bit_cast(v2h, wv.w);
    const int ln = ic >> 1;
    float a[4];
#pragma unroll
    for (int s = 0; s < 4; ++s) {
      const int L = ln + 16 * s;
      float acc;
      if ((ic & 1) == 0) {
        acc = dot2(xlane<0>(xr0, xr1, L), w0, 0.f);
        acc = dot2(xlane<1>(xr0, xr1, L), w1, acc);
        acc = dot2(xlane<2>(xr0, xr1, L), w2, acc);
        acc = dot2(xlane<3>(xr0, xr1, L), w3, acc);
      } else {
        acc = dot2(xlane<4>(xr0, xr1, L), w0, 0.f);
        acc = dot2(xlane<5>(xr0, xr1, L), w1, acc);
        acc = dot2(xlane<6>(xr0, xr1, L), w2, acc);
        acc = dot2(xlane<7>(xr0, xr1, L), w3, acc);
      }
      a[s] = acc;
    }
    oA += (v2f){a[0], a[1]};
    oB += (v2f){a[2], a[3]};
    uhA[ic] = pack2h(a[0], a[1]);
    uhB[ic] = pack2h(a[2], a[3]);
  }

  float* bp0 = &b_lds[0][dc][nc];  // transposed-target bases for this thread
  float* bp1 = &b_lds[1][dc][nc];
  float* bp2 = &b_lds[2][dc][nc];
  float* bp3 = &b_lds[3][dc][nc];

  // ---- routing round 0: b = 0 => c = 1/16 ----
  {
    v2f vA = squash2(oA * (v2f){0.0625f, 0.0625f});
    v2f vB = squash2(oB * (v2f){0.0625f, 0.0625f});
    b_update2<true>(pack2h(vA.x, vA.y), uhA, dc, bp0, bp1);
    b_update2<true>(pack2h(vB.x, vB.y), uhB, dc, bp2, bp3);
  }
  __syncthreads();

  // ---- rounds 1, 2 ----
#pragma unroll
  for (int r = 1; r < 3; ++r) {
    {  // distributed softmax over nc: 256 threads. thread -> (ss, ic, half)
      const int ss  = t >> 6;         // sample 0..3 (wave-uniform)
      const int icc = (t >> 1) & 31;  // column (ic)
      const int q   = t & 1;          // nc rows 8q..8q+7
      // no max-subtraction: |b| bounded far below exp overflow; shift-invariant.
      const v4f bL = *(const v4f*)&b_lds[ss][icc][8 * q + 0];  // ds_read_b128
      const v4f bH = *(const v4f*)&b_lds[ss][icc][8 * q + 4];  // ds_read_b128
      float e0 = __expf(bL.x), e1 = __expf(bL.y), e2 = __expf(bL.z), e3 = __expf(bL.w);
      float e4 = __expf(bH.x), e5 = __expf(bH.y), e6 = __expf(bH.z), e7 = __expf(bH.w);
      float ps = ((e0 + e1) + (e2 + e3)) + ((e4 + e5) + (e6 + e7));
      ps += dppf<0xB1>(ps);  // + lane^1 (partner half) -> full 16-row sum
      float inv = __builtin_amdgcn_rcpf(ps);
      _Float16* cw = (_Float16*)(ss < 2 ? cAh : cBh) + (ss & 1);  // pair component
      cw[((8 * q + 0) * CSTRIDE + icc) * 2] = (_Float16)(e0 * inv);
      cw[((8 * q + 1) * CSTRIDE + icc) * 2] = (_Float16)(e1 * inv);
      cw[((8 * q + 2) * CSTRIDE + icc) * 2] = (_Float16)(e2 * inv);
      cw[((8 * q + 3) * CSTRIDE + icc) * 2] = (_Float16)(e3 * inv);
      cw[((8 * q + 4) * CSTRIDE + icc) * 2] = (_Float16)(e4 * inv);
      cw[((8 * q + 5) * CSTRIDE + icc) * 2] = (_Float16)(e5 * inv);
      cw[((8 * q + 6) * CSTRIDE + icc) * 2] = (_Float16)(e6 * inv);
      cw[((8 * q + 7) * CSTRIDE + icc) * 2] = (_Float16)(e7 * inv);
    }
    __syncthreads();

    // c.uh: 8 ds_read_b128 broadcasts per table (4 ic-pairs per b128).
    const v8h* crA = (const v8h*)(cAh + nc * CSTRIDE);
    const v8h* crB = (const v8h*)(cBh + nc * CSTRIDE);
    v2h ohA = (v2h){(_Float16)0.f, (_Float16)0.f};
    v2h ohB = (v2h){(_Float16)0.f, (_Float16)0.f};
#pragma unroll
    for (int blk = 0; blk < 4; ++blk) {
      uint4 ua = __builtin_bit_cast(uint4, crA[blk]);      // ic 4blk..4blk+3
      uint4 ub = __builtin_bit_cast(uint4, crA[blk + 4]);  // ic 16+4blk..
      ohA = __builtin_elementwise_fma(__builtin_bit_cast(v2h, ua.x), uhA[4 * blk + 0], ohA);
      ohA = __builtin_elementwise_fma(__builtin_bit_cast(v2h, ua.y), uhA[4 * blk + 1], ohA);
      ohA = __builtin_elementwise_fma(__builtin_bit_cast(v2h, ua.z), uhA[4 * blk + 2], ohA);
      ohA = __builtin_elementwise_fma(__builtin_bit_cast(v2h, ua.w), uhA[4 * blk + 3], ohA);
      ohA = __builtin_elementwise_fma(__builtin_bit_cast(v2h, ub.x), uhA[16 + 4 * blk + 0], ohA);
      ohA = __builtin_elementwise_fma(__builtin_bit_cast(v2h, ub.y), uhA[16 + 4 * blk + 1], ohA);
      ohA = __builtin_elementwise_fma(__builtin_bit_cast(v2h, ub.z), uhA[16 + 4 * blk + 2], ohA);
      ohA = __builtin_elementwise_fma(__builtin_bit_cast(v2h, ub.w), uhA[16 + 4 * blk + 3], ohA);
      uint4 va = __builtin_bit_cast(uint4, crB[blk]);
      uint4 vb = __builtin_bit_cast(uint4, crB[blk + 4]);
      ohB = __builtin_elementwise_fma(__builtin_bit_cast(v2h, va.x), uhB[4 * blk + 0], ohB);
      ohB = __builtin_elementwise_fma(__builtin_bit_cast(v2h, va.y), uhB[4 * blk + 1], ohB);
      ohB = __builtin_elementwise_fma(__builtin_bit_cast(v2h, va.z), uhB[4 * blk + 2], ohB);
      ohB = __builtin_elementwise_fma(__builtin_bit_cast(v2h, va.w), uhB[4 * blk + 3], ohB);
      ohB = __builtin_elementwise_fma(__builtin_bit_cast(v2h, vb.x), uhB[16 + 4 * blk + 0], ohB);
      ohB = __builtin_elementwise_fma(__builtin_bit_cast(v2h, vb.y), uhB[16 + 4 * blk + 1], ohB);
      ohB = __builtin_elementwise_fma(__builtin_bit_cast(v2h, vb.z), uhB[16 + 4 * blk + 2], ohB);
      ohB = __builtin_elementwise_fma(__builtin_bit_cast(v2h, vb.w), uhB[16 + 4 * blk + 3], ohB);
    }
    v2f vA = squash2((v2f){(float)ohA.x, (float)ohA.y});
    v2f vB = squash2((v2f){(float)ohB.x, (float)ohB.y});
    if (r == 2) {
      out[(s0 + 0) * 256 + t] = vA.x;
      out[(s0 + 1) * 256 + t] = vA.y;
      out[(s0 + 2) * 256 + t] = vB.x;
      out[(s0 + 3) * 256 + t] = vB.y;
    } else {
      b_update2<false>(pack2h(vA.x, vA.y), uhA, dc, bp0, bp1);
      b_update2<false>(pack2h(vB.x, vB.y), uhB, dc, bp2, bp3);
      __syncthreads();  // b complete before round-2 softmax; c overwrite safe
    }
  }
}

extern "C" void kernel_launch(void* const* d_in, const int* in_sizes, int n_in,
                              void* d_out, int out_size, void* d_ws, size_t ws_size,
                              hipStream_t stream) {
  const float* x = (const float*)d_in[0];
  const float* W = (const float*)d_in[1];
  _Float16* Wth = (_Float16*)d_ws;           // 128 KB: f16 W-transpose
  _Float16* xh  = (_Float16*)d_ws + 65536;   // 4 MB: f16 x

  prep_kernel<<<1280, 256, 0, stream>>>(W, x, Wth, xh);
  caps_kernel<<<8192 / S, 256, 0, stream>>>(xh, (const uint4*)Wth, (float*)d_out);
}

// Round 7
// 92.348 us; speedup vs baseline: 1.1886x; 1.0579x over previous
//
#include <hip/hip_runtime.h>
#include <hip/hip_bf16.h>

// CapsuleNet dynamic routing, fused per-sample. fp32 I/O:
// x: f32 [8192, 32, 8], W: f32 [32, 8, 256], out: f32 [8192, 16, 16].
// One block = S samples; thread t = (nc = t>>4, dc = t&15) owns column k = t.
// r15: x as wave-uniform s_loads. r16: b128 c-reads, transposed b_lds.
// r17/r18: (256,6) + CSTRIDE 44 (spill fix). r19: S=4, (256,4): BEST, 91.06.
// r20: uniform-addr VMEM x: caps 43->57 REGRESSION (VMEM issue+addr cost).
// r21: readlane x-broadcast: caps 43.0, VALUBusy 71% — neutral vs s_load.
// r22 (this round): REVERT to r19 exactly. Conclusion from r15-r21: caps is
// VALU-work-bound (~30.5us issue floor at 71% busy); x-transport variants
// (s_load / VMEM / readlane) are within 1us of each other; transport is NOT
// the bottleneck. r19 is the measured optimum of 9 configurations.

#define S 4

typedef float    v2f __attribute__((ext_vector_type(2)));
typedef float    v4f __attribute__((ext_vector_type(4)));
typedef _Float16 v2h __attribute__((ext_vector_type(2)));
typedef _Float16 v8h __attribute__((ext_vector_type(8)));

__device__ __forceinline__ v2h pack2h(float a, float b) {
  return __builtin_bit_cast(v2h, __builtin_amdgcn_cvt_pkrtz(a, b));  // v_cvt_pkrtz_f16_f32
}

// DPP cross-lane: value of `x` from lane (lane ^ k) within a 16-lane row.
// 0xB1 = quad_perm[1,0,3,2] (xor1)  0x4E = quad_perm[2,3,0,1] (xor2)
// 0x128 = row_ror:8 (xor8)  0x141 = row_half_mirror  0x140 = row_mirror
template <int CTRL>
__device__ __forceinline__ float dppf(float x) {
  return __builtin_bit_cast(float,
      __builtin_amdgcn_update_dpp(0, __builtin_bit_cast(int, x), CTRL, 0xF, 0xF, true));
}
template <int CTRL>
__device__ __forceinline__ v2h dpph(v2h v) {  // both samples in one DPP
  return __builtin_bit_cast(v2h,
      __builtin_amdgcn_update_dpp(0, __builtin_bit_cast(int, v), CTRL, 0xF, 0xF, true));
}
// Masked DPP keeping `old` on disabled banks (bound_ctrl=false: keep old).
template <int CTRL, int BANK>
__device__ __forceinline__ int dpp_old_i(int old, int x) {
  return __builtin_amdgcn_update_dpp(old, x, CTRL, 0xF, BANK, false);
}
// Deliver partner(lane^4)'s value of s to every lane (validated r10/r13):
// banks 0,2 (lanes 0-3,8-11): from lane+4 via row_shl:4 (0x104);
// banks 1,3 (lanes 4-7,12-15): from lane-4 via row_shr:4 (0x114).
__device__ __forceinline__ v2h xor4t_h(v2h s) {
  int si = __builtin_bit_cast(int, s);
  int ya = dpp_old_i<0x104, 0x5>(0, si);
  return __builtin_bit_cast(v2h, dpp_old_i<0x114, 0xA>(ya, si));
}

#if __has_builtin(__builtin_amdgcn_fdot2)
__device__ __forceinline__ float dot2(v2h a, v2h b, float c) {
  return __builtin_amdgcn_fdot2(a, b, c, false);  // v_dot2_f32_f16
}
#else
__device__ __forceinline__ float dot2(v2h a, v2h b, float c) {
  return fmaf((float)a.x, (float)b.x, fmaf((float)a.y, (float)b.y, c));
}
#endif

// Fused prep: blocks 0..255: W[ic][id][k](f32) -> Wth[ic][k][id](f16), NO
// permute; blocks 256..1279: x (f32) -> xh (f16), 8 elems/thread.
__global__ __launch_bounds__(256) void prep_kernel(const float* __restrict__ W,
                                                   const float* __restrict__ x,
                                                   _Float16* __restrict__ Wth,
                                                   _Float16* __restrict__ xh) {
  int bid = blockIdx.x;
  if (bid < 256) {
    int o  = bid * 256 + threadIdx.x;
    int ic = o >> 11;
    int k  = (o >> 3) & 255;
    int id = o & 7;
    Wth[o] = (_Float16)W[(ic * 8 + id) * 256 + k];
  } else {
    int tid = (bid - 256) * 256 + threadIdx.x;
    const float4* xp = (const float4*)x + tid * 2;
    float4 f0 = xp[0], f1 = xp[1];
    v2h h0 = {(_Float16)f0.x, (_Float16)f0.y};
    v2h h1 = {(_Float16)f0.z, (_Float16)f0.w};
    v2h h2 = {(_Float16)f1.x, (_Float16)f1.y};
    v2h h3 = {(_Float16)f1.z, (_Float16)f1.w};
    uint4 o;
    o.x = __builtin_bit_cast(unsigned, h0);
    o.y = __builtin_bit_cast(unsigned, h1);
    o.z = __builtin_bit_cast(unsigned, h2);
    o.w = __builtin_bit_cast(unsigned, h3);
    ((uint4*)xh)[tid] = o;
  }
}

// squash over the 16 dc lanes, both samples at once; DPP-only reduction (f32).
__device__ __forceinline__ v2f squash2(v2f o) {
  v2f s2 = o * o;
  s2.x += dppf<0xB1>(s2.x);   s2.y += dppf<0xB1>(s2.y);    // + lane^1
  s2.x += dppf<0x4E>(s2.x);   s2.y += dppf<0x4E>(s2.y);    // + lane^2
  s2.x += dppf<0x141>(s2.x);  s2.y += dppf<0x141>(s2.y);   // + lane^7
  s2.x += dppf<0x140>(s2.x);  s2.y += dppf<0x140>(s2.y);   // + lane^15
  s2 += (v2f){1e-7f, 1e-7f};
  v2f sc;
  sc.x = s2.x * __builtin_amdgcn_rsqf(s2.x) * __builtin_amdgcn_rcpf(1.f + s2.x);
  sc.y = s2.y * __builtin_amdgcn_rsqf(s2.y) * __builtin_amdgcn_rcpf(1.f + s2.y);
  return o * sc;  // sqrt(s2)/(1+s2) * o
}

// Butterfly transpose-reduction on NORMAL-order packed-f16 uh (selects are
// single 32-bit cndmasks moving both samples). Lane dc lands b[icb+dc][nc]
// (f32, transposed layout: bp* pre-offset to &b_lds[s][dc][nc], row stride
// 20 floats; icb*20 is a compile-time ds offset immediate).
// Levels 8/2/1 via DPP xor; level 4 via the masked dual-DPP transport.
template <bool ASSIGN>
__device__ __forceinline__ void b_update2(v2h vh, const v2h* uh, int dc,
                                          float* bp0, float* bp1) {
#pragma unroll
  for (int icb = 0; icb < 32; icb += 16) {
    v2h a[16];
#pragma unroll
    for (int j = 0; j < 16; ++j) a[j] = vh * uh[icb + j];  // pk_mul_f16
    v2h b8[8];
    const bool u8 = (dc & 8) != 0;
#pragma unroll
    for (int j = 0; j < 8; ++j) {
      v2h send = u8 ? a[j] : a[j + 8];
      v2h recv = dpph<0x128>(send);              // partner(lane^8)'s send
      b8[j] = (u8 ? a[j + 8] : a[j]) + recv;
    }
    v2h c4[4];
    const bool u4 = (dc & 4) != 0;
#pragma unroll
    for (int j = 0; j < 4; ++j) {
      v2h send = u4 ? b8[j] : b8[j + 4];
      v2h recv = xor4t_h(send);                  // partner(lane^4)'s send
      c4[j] = (u4 ? b8[j + 4] : b8[j]) + recv;
    }
    v2h d2[2];
    const bool u2 = (dc & 2) != 0;
#pragma unroll
    for (int j = 0; j < 2; ++j) {
      v2h send = u2 ? c4[j] : c4[j + 2];
      v2h recv = dpph<0x4E>(send);               // partner(lane^2)'s send
      d2[j] = (u2 ? c4[j + 2] : c4[j]) + recv;
    }
    const bool u1 = (dc & 1) != 0;
    v2h send = u1 ? d2[0] : d2[1];
    v2h recv = dpph<0xB1>(send);                 // partner(lane^1)'s send
    v2h e = (u1 ? d2[1] : d2[0]) + recv;
    float e0 = (float)e.x, e1 = (float)e.y;
    if (ASSIGN) { bp0[icb * 20] = e0;  bp1[icb * 20] = e1; }
    else        { bp0[icb * 20] += e0; bp1[icb * 20] += e1; }
  }
}

#define CSTRIDE 44  // v2h per c-row: 176 B rows (16B-aligned). Read side: 4
                    // nc-row b128 broadcasts start at banks (12nc+4blk)%32 ->
                    // 4 disjoint 4-bank spans. Write side: 2 lanes/bank (free).

__global__ __launch_bounds__(256, 4) void caps_kernel(const _Float16* __restrict__ xh,
                                                      const uint4* __restrict__ Wt4,
                                                      float* __restrict__ out) {
  const int t  = threadIdx.x;
  const int nc = t >> 4;
  const int dc = t & 15;
  const int s0 = blockIdx.x * S;

  // b transposed: [sample][ic 0..31][nc 0..15 padded to 20].
  // softmax reads b[ss][ic][8q..8q+7] as TWO ds_read_b128 (16B-aligned).
  __shared__ __align__(16) float b_lds[S][32][20];
  __shared__ __align__(16) v2h cAh[16 * CSTRIDE];  // c pairs, samples (0,1)
  __shared__ __align__(16) v2h cBh[16 * CSTRIDE];  // c pairs, samples (2,3)

  v2h uhA[32], uhB[32];                // packed (s0,s1) / (s2,s3)
  v2f oA = (v2f){0.f, 0.f};
  v2f oB = (v2f){0.f, 0.f};

  // ---- u_hat: wave-uniform x (s_load, free) + ONE b128 W load per ic,
  //      amortized over 4 samples ----
  const v2h* xp0 = (const v2h*)(xh + (s0 + 0) * 256);  // block-uniform -> s_load
  const v2h* xp1 = (const v2h*)(xh + (s0 + 1) * 256);
  const v2h* xp2 = (const v2h*)(xh + (s0 + 2) * 256);
  const v2h* xp3 = (const v2h*)(xh + (s0 + 3) * 256);
#pragma unroll
  for (int ic = 0; ic < 32; ++ic) {
    uint4 wv = Wt4[ic * 256 + t];  // 8 f16 weights, one coalesced dwordx4
    v2h w0 = __builtin_bit_cast(v2h, wv.x);
    v2h w1 = __builtin_bit_cast(v2h, wv.y);
    v2h w2 = __builtin_bit_cast(v2h, wv.z);
    v2h w3 = __builtin_bit_cast(v2h, wv.w);
    float a0 = dot2(xp0[ic * 4 + 3], w3, dot2(xp0[ic * 4 + 2], w2,
               dot2(xp0[ic * 4 + 1], w1, dot2(xp0[ic * 4 + 0], w0, 0.f))));
    float a1 = dot2(xp1[ic * 4 + 3], w3, dot2(xp1[ic * 4 + 2], w2,
               dot2(xp1[ic * 4 + 1], w1, dot2(xp1[ic * 4 + 0], w0, 0.f))));
    float a2 = dot2(xp2[ic * 4 + 3], w3, dot2(xp2[ic * 4 + 2], w2,
               dot2(xp2[ic * 4 + 1], w1, dot2(xp2[ic * 4 + 0], w0, 0.f))));
    float a3 = dot2(xp3[ic * 4 + 3], w3, dot2(xp3[ic * 4 + 2], w2,
               dot2(xp3[ic * 4 + 1], w1, dot2(xp3[ic * 4 + 0], w0, 0.f))));
    oA += (v2f){a0, a1};
    oB += (v2f){a2, a3};
    uhA[ic] = pack2h(a0, a1);
    uhB[ic] = pack2h(a2, a3);
  }

  float* bp0 = &b_lds[0][dc][nc];  // transposed-target bases for this thread
  float* bp1 = &b_lds[1][dc][nc];
  float* bp2 = &b_lds[2][dc][nc];
  float* bp3 = &b_lds[3][dc][nc];

  // ---- routing round 0: b = 0 => c = 1/16 ----
  {
    v2f vA = squash2(oA * (v2f){0.0625f, 0.0625f});
    v2f vB = squash2(oB * (v2f){0.0625f, 0.0625f});
    b_update2<true>(pack2h(vA.x, vA.y), uhA, dc, bp0, bp1);
    b_update2<true>(pack2h(vB.x, vB.y), uhB, dc, bp2, bp3);
  }
  __syncthreads();

  // ---- rounds 1, 2 ----
#pragma unroll
  for (int r = 1; r < 3; ++r) {
    {  // distributed softmax over nc: 256 threads. thread -> (ss, ic, half)
      const int ss  = t >> 6;         // sample 0..3 (wave-uniform)
      const int icc = (t >> 1) & 31;  // column (ic)
      const int q   = t & 1;          // nc rows 8q..8q+7
      // no max-subtraction: |b| bounded far below exp overflow; shift-invariant.
      const v4f bL = *(const v4f*)&b_lds[ss][icc][8 * q + 0];  // ds_read_b128
      const v4f bH = *(const v4f*)&b_lds[ss][icc][8 * q + 4];  // ds_read_b128
      float e0 = __expf(bL.x), e1 = __expf(bL.y), e2 = __expf(bL.z), e3 = __expf(bL.w);
      float e4 = __expf(bH.x), e5 = __expf(bH.y), e6 = __expf(bH.z), e7 = __expf(bH.w);
      float ps = ((e0 + e1) + (e2 + e3)) + ((e4 + e5) + (e6 + e7));
      ps += dppf<0xB1>(ps);  // + lane^1 (partner half) -> full 16-row sum
      float inv = __builtin_amdgcn_rcpf(ps);
      _Float16* cw = (_Float16*)(ss < 2 ? cAh : cBh) + (ss & 1);  // pair component
      cw[((8 * q + 0) * CSTRIDE + icc) * 2] = (_Float16)(e0 * inv);
      cw[((8 * q + 1) * CSTRIDE + icc) * 2] = (_Float16)(e1 * inv);
      cw[((8 * q + 2) * CSTRIDE + icc) * 2] = (_Float16)(e2 * inv);
      cw[((8 * q + 3) * CSTRIDE + icc) * 2] = (_Float16)(e3 * inv);
      cw[((8 * q + 4) * CSTRIDE + icc) * 2] = (_Float16)(e4 * inv);
      cw[((8 * q + 5) * CSTRIDE + icc) * 2] = (_Float16)(e5 * inv);
      cw[((8 * q + 6) * CSTRIDE + icc) * 2] = (_Float16)(e6 * inv);
      cw[((8 * q + 7) * CSTRIDE + icc) * 2] = (_Float16)(e7 * inv);
    }
    __syncthreads();

    // c.uh: 8 ds_read_b128 broadcasts per table (4 ic-pairs per b128).
    const v8h* crA = (const v8h*)(cAh + nc * CSTRIDE);
    const v8h* crB = (const v8h*)(cBh + nc * CSTRIDE);
    v2h ohA = (v2h){(_Float16)0.f, (_Float16)0.f};
    v2h ohB = (v2h){(_Float16)0.f, (_Float16)0.f};
#pragma unroll
    for (int blk = 0; blk < 4; ++blk) {
      uint4 ua = __builtin_bit_cast(uint4, crA[blk]);      // ic 4blk..4blk+3
      uint4 ub = __builtin_bit_cast(uint4, crA[blk + 4]);  // ic 16+4blk..
      ohA = __builtin_elementwise_fma(__builtin_bit_cast(v2h, ua.x), uhA[4 * blk + 0], ohA);
      ohA = __builtin_elementwise_fma(__builtin_bit_cast(v2h, ua.y), uhA[4 * blk + 1], ohA);
      ohA = __builtin_elementwise_fma(__builtin_bit_cast(v2h, ua.z), uhA[4 * blk + 2], ohA);
      ohA = __builtin_elementwise_fma(__builtin_bit_cast(v2h, ua.w), uhA[4 * blk + 3], ohA);
      ohA = __builtin_elementwise_fma(__builtin_bit_cast(v2h, ub.x), uhA[16 + 4 * blk + 0], ohA);
      ohA = __builtin_elementwise_fma(__builtin_bit_cast(v2h, ub.y), uhA[16 + 4 * blk + 1], ohA);
      ohA = __builtin_elementwise_fma(__builtin_bit_cast(v2h, ub.z), uhA[16 + 4 * blk + 2], ohA);
      ohA = __builtin_elementwise_fma(__builtin_bit_cast(v2h, ub.w), uhA[16 + 4 * blk + 3], ohA);
      uint4 va = __builtin_bit_cast(uint4, crB[blk]);
      uint4 vb = __builtin_bit_cast(uint4, crB[blk + 4]);
      ohB = __builtin_elementwise_fma(__builtin_bit_cast(v2h, va.x), uhB[4 * blk + 0], ohB);
      ohB = __builtin_elementwise_fma(__builtin_bit_cast(v2h, va.y), uhB[4 * blk + 1], ohB);
      ohB = __builtin_elementwise_fma(__builtin_bit_cast(v2h, va.z), uhB[4 * blk + 2], ohB);
      ohB = __builtin_elementwise_fma(__builtin_bit_cast(v2h, va.w), uhB[4 * blk + 3], ohB);
      ohB = __builtin_elementwise_fma(__builtin_bit_cast(v2h, vb.x), uhB[16 + 4 * blk + 0], ohB);
      ohB = __builtin_elementwise_fma(__builtin_bit_cast(v2h, vb.y), uhB[16 + 4 * blk + 1], ohB);
      ohB = __builtin_elementwise_fma(__builtin_bit_cast(v2h, vb.z), uhB[16 + 4 * blk + 2], ohB);
      ohB = __builtin_elementwise_fma(__builtin_bit_cast(v2h, vb.w), uhB[16 + 4 * blk + 3], ohB);
    }
    v2f vA = squash2((v2f){(float)ohA.x, (float)ohA.y});
    v2f vB = squash2((v2f){(float)ohB.x, (float)ohB.y});
    if (r == 2) {
      out[(s0 + 0) * 256 + t] = vA.x;
      out[(s0 + 1) * 256 + t] = vA.y;
      out[(s0 + 2) * 256 + t] = vB.x;
      out[(s0 + 3) * 256 + t] = vB.y;
    } else {
      b_update2<false>(pack2h(vA.x, vA.y), uhA, dc, bp0, bp1);
      b_update2<false>(pack2h(vB.x, vB.y), uhB, dc, bp2, bp3);
      __syncthreads();  // b complete before round-2 softmax; c overwrite safe
    }
  }
}

extern "C" void kernel_launch(void* const* d_in, const int* in_sizes, int n_in,
                              void* d_out, int out_size, void* d_ws, size_t ws_size,
                              hipStream_t stream) {
  const float* x = (const float*)d_in[0];
  const float* W = (const float*)d_in[1];
  _Float16* Wth = (_Float16*)d_ws;           // 128 KB: f16 W-transpose
  _Float16* xh  = (_Float16*)d_ws + 65536;   // 4 MB: f16 x

  prep_kernel<<<1280, 256, 0, stream>>>(W, x, Wth, xh);
  caps_kernel<<<8192 / S, 256, 0, stream>>>(xh, (const uint4*)Wth, (float*)d_out);
}